// Round 9
// baseline (484.899 us; speedup 1.0000x reference)
//
#include <hip/hip_runtime.h>

typedef unsigned short u16;
typedef __attribute__((ext_vector_type(8))) short bf16x8;
typedef __attribute__((ext_vector_type(4))) float f32x4;

#define NN 4
#define HH 256
#define WW 256
#define PD 258
#define CIN 64
#define EPSV 1e-5f

__device__ __forceinline__ float b2f(u16 x){ union{unsigned u; float f;} q; q.u = ((unsigned)x)<<16; return q.f; }
__device__ __forceinline__ u16 f2b(float f){ union{float f; unsigned u;} q; q.f = f; unsigned r = q.u + 0x7FFF + ((q.u>>16)&1u); return (u16)(r>>16); }
__device__ __forceinline__ float leakyf(float x){ return x >= 0.f ? x : 0.01f*x; }

// ---------- prep: weights OIHW f32 -> [tap][cout][cin] bf16 ----------
__global__ void prep_kernel(const float* __restrict__ w1, const float* __restrict__ wf,
                            const float* __restrict__ w2, const float* __restrict__ wr,
                            u16* __restrict__ wB1, u16* __restrict__ wBf,
                            u16* __restrict__ wB2, u16* __restrict__ wBr){
  int idx = blockIdx.x*256 + threadIdx.x;
  if (idx < 9*64*64){
    int tap = idx/4096, r = idx%4096, cout = r/64, cin = r%64;
    int src = (cout*64 + cin)*9 + tap;
    wB1[idx] = f2b(w1[src]);
    wB2[idx] = f2b(w2[src]);
  }
  if (idx < 9*80*64){
    int tap = idx/5120, r = idx%5120, cout = r/64, cin = r%64;
    float v = (cout < 72) ? wf[(cout*64 + cin)*9 + tap] : 0.f;
    wBf[idx] = f2b(v);
  }
  if (idx < 64*64){
    int cout = idx/64, cin = idx%64;
    wBr[idx] = f2b(wr[cout*64 + cin]);
  }
}

// ---------- pad_x: x NCHW f32 -> xpad NHWC bf16 [n][258][258][64], zero borders ----------
__global__ __launch_bounds__(256) void padx_kernel(const float* __restrict__ x, u16* __restrict__ xpad){
  int n = blockIdx.x >> 8, h = blockIdx.x & 255, t = threadIdx.x;
  u16* dstrow = xpad + ((size_t)(n*PD + h + 1)*PD)*CIN;
  const uint4 z = {0,0,0,0};
  #pragma unroll
  for (int c8 = 0; c8 < 8; ++c8){
    u16 buf[8];
    #pragma unroll
    for (int j = 0; j < 8; ++j)
      buf[j] = f2b(x[((size_t)(n*64 + c8*8 + j))*65536 + h*256 + t]);
    *(uint4*)(dstrow + (size_t)(t+1)*CIN + c8*8) = *(uint4*)buf;
  }
  if (t == 0)   { for (int c8 = 0; c8 < 8; ++c8) *(uint4*)(dstrow + 0*CIN   + c8*8) = z; }
  if (t == 255) { for (int c8 = 0; c8 < 8; ++c8) *(uint4*)(dstrow + 257*CIN + c8*8) = z; }
  if (h == 0 || h == 255){
    u16* brow = xpad + ((size_t)(n*PD + (h == 0 ? 0 : 257))*PD)*CIN;
    for (int p = t; p < PD; p += 256)
      for (int c8 = 0; c8 < 8; ++c8) *(uint4*)(brow + (size_t)p*CIN + c8*8) = z;
  }
}

// ---------- reflect borders of y1pad ----------
__global__ void reflect_kernel(u16* __restrict__ y1pad){
  int idx = blockIdx.x*256 + threadIdx.x;
  if (idx >= 4*1028*8) return;
  int n = idx/(1028*8), rem = idx%(1028*8), p = rem >> 3, cc = rem & 7;
  int pr, pc;
  if      (p < 258)  { pr = 0;   pc = p; }
  else if (p < 516)  { pr = 257; pc = p - 258; }
  else if (p < 772)  { pr = 1 + (p - 516); pc = 0; }
  else               { pr = 1 + (p - 772); pc = 257; }
  int sr = (pr == 0) ? 2 : ((pr == 257) ? 255 : pr);
  int sc = (pc == 0) ? 2 : ((pc == 257) ? 255 : pc);
  uint4 v = *(const uint4*)(y1pad + ((size_t)(n*PD + sr)*PD + sc)*CIN + cc*8);
  *(uint4*)(y1pad + ((size_t)(n*PD + pr)*PD + pc)*CIN + cc*8) = v;
}

// ---------- MFMA conv core: 16 px/wave (64 px/block), LDS-staged weights, direct A loads ----------
// MODE 0: conv1 (A=xpad zero-padded, +bias, out=y1pad interior bf16)
// MODE 1: convF (A=y1pad incl. reflect ring, out=sig [n][hw][80] bf16, + BN sum/sumsq atomics)
// MODE 2: conv2 (A=y2pad pre-transformed+zero ring, epilogue leaky(+b2) + 1x1(xpad,wBr) + br -> f32 NCHW)
template<int NF, int MODE>
__global__ __launch_bounds__(256, (NF == 5) ? 5 : 6) void conv_mfma(
    const u16* __restrict__ Ain, const u16* __restrict__ wB, const float* __restrict__ bias,
    u16* __restrict__ outB, float* __restrict__ outF,
    const u16* __restrict__ xpad, const u16* __restrict__ wBr,
    const float* __restrict__ br,
    float* __restrict__ bnsum, float* __restrict__ bnsumsq){

  constexpr int NC  = NF*16;
  constexpr int NCP = NC + 8;                 // padded row stride for Bx
  constexpr int NST = (NC*8 + 255)/256;       // 16B chunks per thread for one tap's weights
  __shared__ __align__(16) u16 wlds[2][NC*64];
  __shared__ __align__(16) u16 Bx[(MODE < 2) ? 64*NCP : 8];
  __shared__ float bnpart[(MODE == 1) ? 4 : 1][NF][16][2];

  int t = threadIdx.x, lane = t & 63, wv = t >> 6;
  int bid = blockIdx.x;
  int sb = (bid & 7)*512 + (bid >> 3);        // XCD-chunked swizzle (bijective: 4096 = 8*512)
  int n = sb >> 10, r = sb & 1023, h = r >> 2, wt = r & 3, w0 = wt*64;
  int l15 = lane & 15, l4 = lane >> 4;

  const u16* An = Ain + (size_t)n*PD*PD*CIN;
  const int pc0 = w0 + wv*16 + l15;           // + dw gives padded col

  f32x4 acc[NF];
  #pragma unroll
  for (int f = 0; f < NF; ++f) acc[f] = (f32x4){0.f,0.f,0.f,0.f};

  // prologue: stage tap 0 weights into wlds[0] (coalesced, XOR-swizzled)
  {
    const uint4* wsrc = (const uint4*)(wB);
    #pragma unroll
    for (int s = 0; s < NST; ++s){
      int idx = t + s*256;
      if (idx < NC*8){
        int row = idx >> 3, ch = idx & 7;
        *(uint4*)((char*)wlds[0] + row*128 + ((ch<<4) ^ ((row & 7)<<4))) = wsrc[idx];
      }
    }
  }
  __syncthreads();

  #pragma unroll
  for (int tap = 0; tap < 9; ++tap){
    const int cb = tap & 1, nb = cb ^ 1;
    const int dh = tap/3, dw = tap%3;
    // issue next-tap weight staging loads early (write after MFMAs)
    uint4 streg[NST];
    if (tap < 8){
      const uint4* wsrc = (const uint4*)(wB + (size_t)(tap+1)*NC*64);
      #pragma unroll
      for (int s = 0; s < NST; ++s){
        int idx = t + s*256;
        if (idx < NC*8) streg[s] = wsrc[idx];
      }
    }
    const u16* rowp = An + ((size_t)(h + dh)*PD)*CIN;
    // per-ks to cap register liveness: weights (LDS) + one A fragment + 4-5 MFMAs
    #pragma unroll
    for (int ks = 0; ks < 2; ++ks){
      bf16x8 afr = *(const bf16x8*)(rowp + (size_t)(pc0 + dw)*CIN + (ks*4 + l4)*8);
      #pragma unroll
      for (int f = 0; f < NF; ++f){
        int row = f*16 + l15;
        bf16x8 wfr = *(const bf16x8*)((const char*)wlds[cb] + row*128 + ((ks*64 + l4*16) ^ ((row & 7)<<4)));
        acc[f] = __builtin_amdgcn_mfma_f32_16x16x32_bf16(afr, wfr, acc[f], 0, 0, 0);
      }
    }
    // write staged weights to the other buffer, then barrier
    if (tap < 8){
      #pragma unroll
      for (int s = 0; s < NST; ++s){
        int idx = t + s*256;
        if (idx < NC*8){
          int row = idx >> 3, ch = idx & 7;
          *(uint4*)((char*)wlds[nb] + row*128 + ((ch<<4) ^ ((row & 7)<<4))) = streg[s];
        }
      }
    }
    __syncthreads();
  }

  if (MODE < 2){
    if (MODE == 1){
      #pragma unroll
      for (int f = 0; f < NF; ++f){
        float s = 0.f, q = 0.f;
        #pragma unroll
        for (int reg = 0; reg < 4; ++reg){ float v = acc[f][reg]; s += v; q += v*v; }
        s += __shfl_xor(s, 16); q += __shfl_xor(q, 16);
        s += __shfl_xor(s, 32); q += __shfl_xor(q, 32);
        if (l4 == 0){ bnpart[wv][f][l15][0] = s; bnpart[wv][f][l15][1] = q; }
      }
    }
    #pragma unroll
    for (int f = 0; f < NF; ++f){
      int cout = f*16 + l15;
      float bv = (MODE == 0) ? bias[cout] : 0.f;
      #pragma unroll
      for (int reg = 0; reg < 4; ++reg){
        int px = wv*16 + l4*4 + reg;
        Bx[px*NCP + cout] = f2b(acc[f][reg] + bv);
      }
    }
    __syncthreads();
    const int nch = NC/8;
    for (int idx = t; idx < 64*nch; idx += 256){
      int px = idx/nch, c8 = idx - px*nch;
      uint4 v = *(const uint4*)(Bx + px*NCP + c8*8);
      if (MODE == 0)
        *(uint4*)(outB + ((size_t)(n*PD + h + 1)*PD + (w0 + 1 + px))*CIN + c8*8) = v;
      else
        *(uint4*)(outB + ((size_t)(n*65536 + h*256 + w0 + px))*80 + c8*8) = v;
    }
    if (MODE == 1 && t < 160){
      int c = t >> 1, which = t & 1;
      if (c < 72){
        float v = bnpart[0][c>>4][c&15][which] + bnpart[1][c>>4][c&15][which]
                + bnpart[2][c>>4][c&15][which] + bnpart[3][c>>4][c&15][which];
        atomicAdd(which ? &bnsumsq[c] : &bnsum[c], v);
      }
    }
  } else {
    // streaming epilogue: out = leaky(conv + b2) + 1x1(x) + br, store f32 NCHW
    const u16* Xn = xpad + ((size_t)(n*PD + h + 1)*PD + 1)*CIN;
    bf16x8 xf0 = *(const bf16x8*)(Xn + (size_t)pc0*CIN + l4*8);
    bf16x8 xf1 = *(const bf16x8*)(Xn + (size_t)pc0*CIN + 32 + l4*8);
    #pragma unroll
    for (int f = 0; f < NF; ++f){
      int cout = f*16 + l15;
      bf16x8 b0 = *(const bf16x8*)(wBr + ((size_t)cout)*64 + l4*8);
      bf16x8 b1 = *(const bf16x8*)(wBr + ((size_t)cout)*64 + 32 + l4*8);
      f32x4 tmp = (f32x4){0.f,0.f,0.f,0.f};
      tmp = __builtin_amdgcn_mfma_f32_16x16x32_bf16(xf0, b0, tmp, 0, 0, 0);
      tmp = __builtin_amdgcn_mfma_f32_16x16x32_bf16(xf1, b1, tmp, 0, 0, 0);
      float bv = bias[cout], bb = br[cout];
      float4 o;
      o.x = leakyf(acc[f][0] + bv) + tmp[0] + bb;
      o.y = leakyf(acc[f][1] + bv) + tmp[1] + bb;
      o.z = leakyf(acc[f][2] + bv) + tmp[2] + bb;
      o.w = leakyf(acc[f][3] + bv) + tmp[3] + bb;
      int px = wv*16 + l4*4;
      *(float4*)(outF + ((size_t)(n*64 + cout))*65536 + h*256 + w0 + px) = o;
    }
  }
}

__global__ void bnfinal_kernel(const float* __restrict__ bnsum, const float* __restrict__ bnsumsq,
                               const float* __restrict__ gamma, const float* __restrict__ beta,
                               float* __restrict__ bnscale, float* __restrict__ bnshift){
  int c = threadIdx.x;
  if (c < 72){
    const float M = 262144.f;
    float mu  = bnsum[c] / M;
    float var = bnsumsq[c] / M - mu*mu;
    float sc  = gamma[c] * rsqrtf(var + EPSV);
    bnscale[c] = sc;
    bnshift[c] = beta[c] - mu*sc;
  }
}

// ---------- filter: BN+softmax(72)+spatial filter, channel-complete per thread ----------
__global__ __launch_bounds__(256,2) void filter_kernel(const u16* __restrict__ sig,
                                                       const u16* __restrict__ y1pad,
                                                       const float* __restrict__ bnscale,
                                                       const float* __restrict__ bnshift,
                                                       u16* __restrict__ y2pad,
                                                       float* __restrict__ hinsum,
                                                       float* __restrict__ hinsumsq){
  __shared__ float sc[72], sh[72];
  __shared__ float ov[256][33];
  __shared__ float ps[8][32][2];
  int t = threadIdx.x;
  if (t < 72){ sc[t] = bnscale[t]; sh[t] = bnshift[t]; }
  __syncthreads();
  int bid = blockIdx.x;
  int sb = (bid & 7)*128 + (bid >> 3);          // XCD-chunked swizzle (bijective: 1024 = 8*128)
  int n = sb >> 8, h = sb & 255;

  float sv[72];
  const u16* sp = sig + ((size_t)(n*65536 + h*256 + t))*80;
  #pragma unroll
  for (int i = 0; i < 9; ++i){
    uint4 v = *(const uint4*)(sp + i*8);
    const u16* e = (const u16*)&v;
    #pragma unroll
    for (int j = 0; j < 8; ++j) sv[i*8+j] = b2f(e[j]);
  }
  float mx = -1e30f;
  #pragma unroll
  for (int c = 0; c < 72; ++c){ sv[c] = sv[c]*sc[c] + sh[c]; mx = fmaxf(mx, sv[c]); }
  float sum = 0.f;
  #pragma unroll
  for (int c = 0; c < 72; ++c){ sv[c] = __expf(sv[c] - mx); sum += sv[c]; }
  float inv = -1.f/sum;
  #pragma unroll
  for (int c = 0; c < 72; ++c) sv[c] *= inv;          // sv = -softmax
  #pragma unroll
  for (int g = 0; g < 8; ++g) sv[g*9+4] += 1.f;       // kern = delta - softmax

  int srow[3], scol[3];
  #pragma unroll
  for (int i = 0; i < 3; ++i){
    int ir = h + i - 1; srow[i] = ((ir < 0) ? 1 : (ir > 255 ? 254 : ir)) + 1;
    int ic = t + i - 1; scol[i] = ((ic < 0) ? 1 : (ic > 255 ? 254 : ic)) + 1;
  }

  float o[64];
  #pragma unroll
  for (int c = 0; c < 64; ++c) o[c] = 0.f;
  const u16* yn = y1pad + (size_t)n*PD*PD*CIN;
  #pragma unroll
  for (int i = 0; i < 3; ++i){
    #pragma unroll
    for (int j = 0; j < 3; ++j){
      const u16* pp = yn + ((size_t)srow[i]*PD + scol[j])*CIN;
      #pragma unroll
      for (int c8 = 0; c8 < 8; ++c8){
        uint4 v = *(const uint4*)(pp + c8*8);
        const u16* e = (const u16*)&v;
        float k = sv[(c8)*9 + i*3 + j];
        #pragma unroll
        for (int jj = 0; jj < 8; ++jj) o[c8*8 + jj] = fmaf(k, b2f(e[jj]), o[c8*8 + jj]);
      }
    }
  }

  u16* wp = y2pad + ((size_t)(n*PD + h + 1)*PD + (t + 1))*CIN;
  #pragma unroll
  for (int c8 = 0; c8 < 8; ++c8){
    u16 ob[8];
    #pragma unroll
    for (int jj = 0; jj < 8; ++jj) ob[jj] = f2b(o[c8*8 + jj]);
    *(uint4*)(wp + c8*8) = *(uint4*)ob;
  }

  #pragma unroll
  for (int c = 0; c < 32; ++c) ov[t][c] = o[c];
  __syncthreads();
  {
    int c = t & 31, seg = t >> 5;
    float s = 0.f, q = 0.f;
    #pragma unroll
    for (int rr = 0; rr < 32; ++rr){
      float v = ov[seg*32 + rr][c];
      s += v; q += v*v;
    }
    ps[seg][c][0] = s; ps[seg][c][1] = q;
  }
  __syncthreads();
  if (t < 64){
    int c = t >> 1, which = t & 1;
    float v = 0.f;
    #pragma unroll
    for (int seg = 0; seg < 8; ++seg) v += ps[seg][c][which];
    atomicAdd(which ? &hinsumsq[n*32 + c] : &hinsum[n*32 + c], v);
  }
}

__global__ void hinfinal_kernel(const float* __restrict__ hinsum, const float* __restrict__ hinsumsq,
                                float* __restrict__ hmu, float* __restrict__ hrs){
  int i = threadIdx.x;
  if (i < 128){
    const float M = 65536.f;
    float mu  = hinsum[i] / M;
    float var = hinsumsq[i] / M - mu*mu;
    hmu[i] = mu;
    hrs[i] = rsqrtf(var + EPSV);
  }
}

// ---------- HIN apply + leaky in place on y2pad; zero the pad ring ----------
__global__ __launch_bounds__(256) void hinapply_kernel(u16* __restrict__ y2pad,
                                                       const float* __restrict__ hmu,
                                                       const float* __restrict__ hrs){
  int n = blockIdx.x / PD, pr = blockIdx.x % PD, t = threadIdx.x;
  u16* row = y2pad + (size_t)(n*PD + pr)*PD*CIN;
  bool ringrow = (pr == 0) || (pr == PD-1);
  for (int idx = t; idx < PD*8; idx += 256){
    int px = idx >> 3, cc = idx & 7;
    uint4* p = (uint4*)(row + (size_t)px*CIN + cc*8);
    if (ringrow || px == 0 || px == PD-1){
      uint4 z = {0,0,0,0}; *p = z; continue;
    }
    uint4 v = *p;
    u16* e = (u16*)&v;
    if (cc < 4){
      int cb = n*32 + cc*8;
      #pragma unroll
      for (int j = 0; j < 8; ++j){
        float f = (b2f(e[j]) - hmu[cb+j]) * hrs[cb+j];
        e[j] = f2b(leakyf(f));
      }
    } else {
      #pragma unroll
      for (int j = 0; j < 8; ++j) e[j] = f2b(leakyf(b2f(e[j])));
    }
    *p = v;
  }
}

// ---------- launch ----------
extern "C" void kernel_launch(void* const* d_in, const int* in_sizes, int n_in,
                              void* d_out, int out_size, void* d_ws, size_t ws_size,
                              hipStream_t stream){
  const float* x     = (const float*)d_in[0];
  const float* w1    = (const float*)d_in[1];
  const float* b1    = (const float*)d_in[2];
  const float* wf    = (const float*)d_in[3];
  const float* gamma = (const float*)d_in[4];
  const float* beta  = (const float*)d_in[5];
  const float* w2    = (const float*)d_in[6];
  const float* b2    = (const float*)d_in[7];
  const float* wr    = (const float*)d_in[8];
  const float* br    = (const float*)d_in[9];

  char* ws = (char*)d_ws;
  const size_t PADB = (size_t)NN*PD*PD*CIN*2;   // 34,080,768 bytes
  u16* xpad  = (u16*)(ws);
  u16* y1pad = (u16*)(ws + PADB);
  u16* y2pad = (u16*)(ws + 2*PADB);
  float* stats = (float*)(ws + 3*PADB);
  float* bnsum   = stats;        float* bnsumsq = stats + 80;
  float* bnscale = stats + 160;  float* bnshift = stats + 240;
  float* hinsum  = stats + 320;  float* hinsumsq= stats + 448;
  float* hmu     = stats + 576;  float* hrs     = stats + 704;
  u16* wB1 = (u16*)(ws + 3*PADB + 4096);
  u16* wBf = wB1 + 9*64*64;
  u16* wB2 = wBf + 9*80*64;
  u16* wBr = wB2 + 9*64*64;

  u16* sig = (u16*)d_out;        // 41.9MB bf16, overwritten by conv2's f32 output later
  float* out = (float*)d_out;

  hipMemsetAsync(stats, 0, 4096, stream);
  prep_kernel<<<180, 256, 0, stream>>>(w1, wf, w2, wr, wB1, wBf, wB2, wBr);
  padx_kernel<<<NN*HH, 256, 0, stream>>>(x, xpad);
  conv_mfma<4,0><<<4096, 256, 0, stream>>>(xpad, wB1, b1, y1pad, nullptr, nullptr, nullptr, nullptr, nullptr, nullptr);
  reflect_kernel<<<(4*1028*8 + 255)/256, 256, 0, stream>>>(y1pad);
  conv_mfma<5,1><<<4096, 256, 0, stream>>>(y1pad, wBf, nullptr, sig, nullptr, nullptr, nullptr, nullptr, bnsum, bnsumsq);
  bnfinal_kernel<<<1, 80, 0, stream>>>(bnsum, bnsumsq, gamma, beta, bnscale, bnshift);
  filter_kernel<<<NN*HH, 256, 0, stream>>>(sig, y1pad, bnscale, bnshift, y2pad, hinsum, hinsumsq);
  hinfinal_kernel<<<1, 128, 0, stream>>>(hinsum, hinsumsq, hmu, hrs);
  hinapply_kernel<<<NN*PD, 256, 0, stream>>>(y2pad, hmu, hrs);
  conv_mfma<4,2><<<4096, 256, 0, stream>>>(y2pad, wB2, b2, nullptr, out, xpad, wBr, br, nullptr, nullptr);
}

// Round 10
// 269.420 us; speedup vs baseline: 1.7998x; 1.7998x over previous
//
#include <hip/hip_runtime.h>

typedef unsigned short u16;
typedef __attribute__((ext_vector_type(8))) short bf16x8;
typedef __attribute__((ext_vector_type(4))) float f32x4;
typedef __attribute__((address_space(3))) void lds_void;
typedef __attribute__((address_space(1))) const void gbl_void;

#define NN 4
#define HH 256
#define WW 256
#define PD 258
#define CIN 64
#define EPSV 1e-5f

__device__ __forceinline__ float b2f(u16 x){ union{unsigned u; float f;} q; q.u = ((unsigned)x)<<16; return q.f; }
__device__ __forceinline__ u16 f2b(float f){ union{float f; unsigned u;} q; q.f = f; unsigned r = q.u + 0x7FFF + ((q.u>>16)&1u); return (u16)(r>>16); }
__device__ __forceinline__ float leakyf(float x){ return x >= 0.f ? x : 0.01f*x; }

// ---------- prep: weights OIHW f32 -> fragment-major bf16 [tap][ks][f][lane][8] ----------
__global__ void prep_kernel(const float* __restrict__ w1, const float* __restrict__ wf,
                            const float* __restrict__ w2, const float* __restrict__ wr,
                            u16* __restrict__ wB1, u16* __restrict__ wBf,
                            u16* __restrict__ wB2, u16* __restrict__ wBr){
  int idx = blockIdx.x*256 + threadIdx.x;
  if (idx < 36864){                       // NF=4: 9*2*4*64*8
    int e = idx & 7, lane = (idx >> 3) & 63, q = idx >> 9;   // q = (tap*2+ks)*4 + f
    int f = q & 3, ksq = q >> 2, ks = ksq & 1, tap = ksq >> 1;
    int cout = f*16 + (lane & 15);
    int cin  = ks*32 + (lane >> 4)*8 + e;
    wB1[idx] = f2b(w1[(cout*64 + cin)*9 + tap]);
    wB2[idx] = f2b(w2[(cout*64 + cin)*9 + tap]);
  }
  if (idx < 46080){                       // NF=5: 9*2*5*64*8
    int e = idx & 7, lane = (idx >> 3) & 63, q = idx >> 9;   // q = (tap*2+ks)*5 + f
    int f = q % 5, ksq = q / 5, ks = ksq & 1, tap = ksq >> 1;
    int cout = f*16 + (lane & 15);
    int cin  = ks*32 + (lane >> 4)*8 + e;
    float v = (cout < 72) ? wf[(cout*64 + cin)*9 + tap] : 0.f;
    wBf[idx] = f2b(v);
  }
  if (idx < 4096){                        // 1x1: [ks][f][lane][8]
    int e = idx & 7, lane = (idx >> 3) & 63, q = idx >> 9;   // q = ks*4+f
    int f = q & 3, ks = q >> 2;
    int cout = f*16 + (lane & 15);
    int cin  = ks*32 + (lane >> 4)*8 + e;
    wBr[idx] = f2b(wr[cout*64 + cin]);
  }
}

// ---------- pad_x: x NCHW f32 -> xpad NHWC bf16 [n][258][258][64], zero borders ----------
__global__ __launch_bounds__(256) void padx_kernel(const float* __restrict__ x, u16* __restrict__ xpad){
  int n = blockIdx.x >> 8, h = blockIdx.x & 255, t = threadIdx.x;
  u16* dstrow = xpad + ((size_t)(n*PD + h + 1)*PD)*CIN;
  const uint4 z = {0,0,0,0};
  #pragma unroll
  for (int c8 = 0; c8 < 8; ++c8){
    u16 buf[8];
    #pragma unroll
    for (int j = 0; j < 8; ++j)
      buf[j] = f2b(x[((size_t)(n*64 + c8*8 + j))*65536 + h*256 + t]);
    *(uint4*)(dstrow + (size_t)(t+1)*CIN + c8*8) = *(uint4*)buf;
  }
  if (t == 0)   { for (int c8 = 0; c8 < 8; ++c8) *(uint4*)(dstrow + 0*CIN   + c8*8) = z; }
  if (t == 255) { for (int c8 = 0; c8 < 8; ++c8) *(uint4*)(dstrow + 257*CIN + c8*8) = z; }
  if (h == 0 || h == 255){
    u16* brow = xpad + ((size_t)(n*PD + (h == 0 ? 0 : 257))*PD)*CIN;
    for (int p = t; p < PD; p += 256)
      for (int c8 = 0; c8 < 8; ++c8) *(uint4*)(brow + (size_t)p*CIN + c8*8) = z;
  }
}

// ---------- reflect borders of y1pad ----------
__global__ void reflect_kernel(u16* __restrict__ y1pad){
  int idx = blockIdx.x*256 + threadIdx.x;
  if (idx >= 4*1028*8) return;
  int n = idx/(1028*8), rem = idx%(1028*8), p = rem >> 3, cc = rem & 7;
  int pr, pc;
  if      (p < 258)  { pr = 0;   pc = p; }
  else if (p < 516)  { pr = 257; pc = p - 258; }
  else if (p < 772)  { pr = 1 + (p - 516); pc = 0; }
  else               { pr = 1 + (p - 772); pc = 257; }
  int sr = (pr == 0) ? 2 : ((pr == 257) ? 255 : pr);
  int sc = (pc == 0) ? 2 : ((pc == 257) ? 255 : pc);
  uint4 v = *(const uint4*)(y1pad + ((size_t)(n*PD + sr)*PD + sc)*CIN + cc*8);
  *(uint4*)(y1pad + ((size_t)(n*PD + pr)*PD + pc)*CIN + cc*8) = v;
}

// ---------- MFMA conv core: async global_load_lds A-staging (swizzled), barrier-free taps ----------
// A window: 3 rows x 130 px x 64ch = 3120 chunks of 16B, staged linear with inverse-swizzled source.
// Read swizzle: chunk j within a px-row is stored at j ^ (px & 7).
// MODE 0: conv1 (A=xpad, +bias, out=y1pad interior bf16)
// MODE 1: convF (A=y1pad incl. reflect ring, out=sig [n][hw][80] bf16, + BN stats atomics)
// MODE 2: conv2 (A=y2pad pre-transformed, epilogue leaky(+b2) + 1x1(xpad,wBr) + br -> f32 NCHW)
template<int NF, int MODE>
__global__ __launch_bounds__(256, 3) void conv_mfma(
    const u16* __restrict__ Ain, const u16* __restrict__ wB, const float* __restrict__ bias,
    u16* __restrict__ outB, float* __restrict__ outF,
    const u16* __restrict__ xpad, const u16* __restrict__ wBr,
    const float* __restrict__ br,
    float* __restrict__ bnsum, float* __restrict__ bnsumsq){

  constexpr int NC  = NF*16;
  constexpr int NCP = NC + 8;
  __shared__ __align__(16) char smem[3328*16];    // 52 KiB: A window (staging) then reused as Bx/bnpart

  int t = threadIdx.x, lane = t & 63, wv = t >> 6;
  int bid = blockIdx.x;
  int sb = (bid & 7)*256 + (bid >> 3);            // XCD-chunked swizzle (bijective: 2048 = 8*256)
  int n = sb >> 9, r = sb & 511, h = r >> 1, wt = r & 1, w0 = wt*128;
  int l15 = lane & 15, l4 = lane >> 4;
  const int pc0 = w0 + wv*32 + l15;

  // ---- async stage A window (rows h..h+2 padded, cols w0..w0+129) ----
  {
    const u16* base = Ain + ((size_t)(n*PD + h)*PD + w0)*CIN;
    #pragma unroll
    for (int rnd = 0; rnd < 13; ++rnd){
      int c_d = rnd*256 + wv*64 + lane;
      int c = (c_d < 3120) ? c_d : 3119;
      int row = (c >= 2080) ? 2 : ((c >= 1040) ? 1 : 0);
      int rem = c - row*1040;
      int px = rem >> 3, sub = rem & 7;
      int subs = sub ^ (px & 7);
      const u16* src = base + (size_t)row*PD*CIN + (size_t)(px*8 + subs)*8;
      __builtin_amdgcn_global_load_lds((gbl_void*)src,
                                       (lds_void*)(smem + (rnd*256 + wv*64)*16), 16, 0, 0);
    }
  }
  __syncthreads();

  f32x4 acc[2][NF];
  #pragma unroll
  for (int mf = 0; mf < 2; ++mf)
    #pragma unroll
    for (int f = 0; f < NF; ++f) acc[mf][f] = (f32x4){0.f,0.f,0.f,0.f};

  // ---- 9 taps, barrier-free: LDS A-frags + contiguous wave weight loads + MFMA ----
  #pragma unroll
  for (int tap = 0; tap < 9; ++tap){
    const int dh = tap/3, dw = tap%3;
    #pragma unroll
    for (int ks = 0; ks < 2; ++ks){
      bf16x8 wfr[NF];
      #pragma unroll
      for (int f = 0; f < NF; ++f)
        wfr[f] = *(const bf16x8*)(wB + ((size_t)(((tap*2 + ks)*NF + f)*64 + lane))*8);
      #pragma unroll
      for (int mf = 0; mf < 2; ++mf){
        int px = wv*32 + mf*16 + l15 + dw;
        int j  = ks*4 + l4;
        bf16x8 afr = *(const bf16x8*)(smem + ((((dh*130 + px) << 3) + (j ^ (px & 7))) << 4));
        #pragma unroll
        for (int f = 0; f < NF; ++f)
          acc[mf][f] = __builtin_amdgcn_mfma_f32_16x16x32_bf16(afr, wfr[f], acc[mf][f], 0, 0, 0);
      }
    }
  }

  if (MODE < 2){
    __syncthreads();                         // As dead; smem reused as Bx + bnpart
    u16* Bx = (u16*)smem;
    float* bnpart = (float*)(smem + 24576);  // [4][NF][16][2]
    if (MODE == 1){
      #pragma unroll
      for (int f = 0; f < NF; ++f){
        float s = 0.f, q = 0.f;
        #pragma unroll
        for (int mf = 0; mf < 2; ++mf)
          #pragma unroll
          for (int reg = 0; reg < 4; ++reg){ float v = acc[mf][f][reg]; s += v; q += v*v; }
        s += __shfl_xor(s, 16); q += __shfl_xor(q, 16);
        s += __shfl_xor(s, 32); q += __shfl_xor(q, 32);
        if (l4 == 0){
          bnpart[((wv*NF + f)*16 + l15)*2 + 0] = s;
          bnpart[((wv*NF + f)*16 + l15)*2 + 1] = q;
        }
      }
    }
    #pragma unroll
    for (int mf = 0; mf < 2; ++mf)
      #pragma unroll
      for (int f = 0; f < NF; ++f){
        int cout = f*16 + l15;
        float bv = (MODE == 0) ? bias[cout] : 0.f;
        #pragma unroll
        for (int reg = 0; reg < 4; ++reg){
          int px = wv*32 + mf*16 + l4*4 + reg;
          Bx[px*NCP + cout] = f2b(acc[mf][f][reg] + bv);
        }
      }
    __syncthreads();
    const int nch = NC/8;
    for (int idx = t; idx < 128*nch; idx += 256){
      int px = idx/nch, c8 = idx - px*nch;
      uint4 v = *(const uint4*)(Bx + px*NCP + c8*8);
      if (MODE == 0)
        *(uint4*)(outB + ((size_t)(n*PD + h + 1)*PD + (w0 + 1 + px))*CIN + c8*8) = v;
      else
        *(uint4*)(outB + ((size_t)(n*65536 + h*256 + w0 + px))*80 + c8*8) = v;
    }
    if (MODE == 1 && t < 160){
      int c = t >> 1, which = t & 1;
      if (c < 72){
        int fi = c >> 4, li = c & 15;
        float v = bnpart[((0*NF + fi)*16 + li)*2 + which] + bnpart[((1*NF + fi)*16 + li)*2 + which]
                + bnpart[((2*NF + fi)*16 + li)*2 + which] + bnpart[((3*NF + fi)*16 + li)*2 + which];
        atomicAdd(which ? &bnsumsq[c] : &bnsum[c], v);
      }
    }
  } else {
    // streaming epilogue: out = leaky(conv + b2) + 1x1(x) + br, store f32 NCHW
    const u16* Xn = xpad + ((size_t)(n*PD + h + 1)*PD + 1)*CIN;
    #pragma unroll
    for (int mf = 0; mf < 2; ++mf){
      bf16x8 xf0 = *(const bf16x8*)(Xn + (size_t)(pc0 + mf*16)*CIN + l4*8);
      bf16x8 xf1 = *(const bf16x8*)(Xn + (size_t)(pc0 + mf*16)*CIN + 32 + l4*8);
      #pragma unroll
      for (int f = 0; f < NF; ++f){
        int cout = f*16 + l15;
        bf16x8 b0 = *(const bf16x8*)(wBr + ((size_t)((0*NF + f)*64 + lane))*8);
        bf16x8 b1 = *(const bf16x8*)(wBr + ((size_t)((1*NF + f)*64 + lane))*8);
        f32x4 tmp = (f32x4){0.f,0.f,0.f,0.f};
        tmp = __builtin_amdgcn_mfma_f32_16x16x32_bf16(xf0, b0, tmp, 0, 0, 0);
        tmp = __builtin_amdgcn_mfma_f32_16x16x32_bf16(xf1, b1, tmp, 0, 0, 0);
        float bv = bias[cout], bb = br[cout];
        float4 o;
        o.x = leakyf(acc[mf][f][0] + bv) + tmp[0] + bb;
        o.y = leakyf(acc[mf][f][1] + bv) + tmp[1] + bb;
        o.z = leakyf(acc[mf][f][2] + bv) + tmp[2] + bb;
        o.w = leakyf(acc[mf][f][3] + bv) + tmp[3] + bb;
        int px = wv*32 + mf*16 + l4*4;
        *(float4*)(outF + ((size_t)(n*64 + cout))*65536 + h*256 + w0 + px) = o;
      }
    }
  }
}

__global__ void bnfinal_kernel(const float* __restrict__ bnsum, const float* __restrict__ bnsumsq,
                               const float* __restrict__ gamma, const float* __restrict__ beta,
                               float* __restrict__ bnscale, float* __restrict__ bnshift){
  int c = threadIdx.x;
  if (c < 72){
    const float M = 262144.f;
    float mu  = bnsum[c] / M;
    float var = bnsumsq[c] / M - mu*mu;
    float sc  = gamma[c] * rsqrtf(var + EPSV);
    bnscale[c] = sc;
    bnshift[c] = beta[c] - mu*sc;
  }
}

// ---------- filter: BN+softmax(72)+spatial filter, channel-complete per thread ----------
__global__ __launch_bounds__(256,2) void filter_kernel(const u16* __restrict__ sig,
                                                       const u16* __restrict__ y1pad,
                                                       const float* __restrict__ bnscale,
                                                       const float* __restrict__ bnshift,
                                                       u16* __restrict__ y2pad,
                                                       float* __restrict__ hinsum,
                                                       float* __restrict__ hinsumsq){
  __shared__ float sc[72], sh[72];
  __shared__ float ov[256][33];
  __shared__ float ps[8][32][2];
  int t = threadIdx.x;
  if (t < 72){ sc[t] = bnscale[t]; sh[t] = bnshift[t]; }
  __syncthreads();
  int bid = blockIdx.x;
  int sb = (bid & 7)*128 + (bid >> 3);
  int n = sb >> 8, h = sb & 255;

  float sv[72];
  const u16* sp = sig + ((size_t)(n*65536 + h*256 + t))*80;
  #pragma unroll
  for (int i = 0; i < 9; ++i){
    uint4 v = *(const uint4*)(sp + i*8);
    const u16* e = (const u16*)&v;
    #pragma unroll
    for (int j = 0; j < 8; ++j) sv[i*8+j] = b2f(e[j]);
  }
  float mx = -1e30f;
  #pragma unroll
  for (int c = 0; c < 72; ++c){ sv[c] = sv[c]*sc[c] + sh[c]; mx = fmaxf(mx, sv[c]); }
  float sum = 0.f;
  #pragma unroll
  for (int c = 0; c < 72; ++c){ sv[c] = __expf(sv[c] - mx); sum += sv[c]; }
  float inv = -1.f/sum;
  #pragma unroll
  for (int c = 0; c < 72; ++c) sv[c] *= inv;
  #pragma unroll
  for (int g = 0; g < 8; ++g) sv[g*9+4] += 1.f;

  int srow[3], scol[3];
  #pragma unroll
  for (int i = 0; i < 3; ++i){
    int ir = h + i - 1; srow[i] = ((ir < 0) ? 1 : (ir > 255 ? 254 : ir)) + 1;
    int ic = t + i - 1; scol[i] = ((ic < 0) ? 1 : (ic > 255 ? 254 : ic)) + 1;
  }

  float o[64];
  #pragma unroll
  for (int c = 0; c < 64; ++c) o[c] = 0.f;
  const u16* yn = y1pad + (size_t)n*PD*PD*CIN;
  #pragma unroll
  for (int i = 0; i < 3; ++i){
    #pragma unroll
    for (int j = 0; j < 3; ++j){
      const u16* pp = yn + ((size_t)srow[i]*PD + scol[j])*CIN;
      #pragma unroll
      for (int c8 = 0; c8 < 8; ++c8){
        uint4 v = *(const uint4*)(pp + c8*8);
        const u16* e = (const u16*)&v;
        float k = sv[(c8)*9 + i*3 + j];
        #pragma unroll
        for (int jj = 0; jj < 8; ++jj) o[c8*8 + jj] = fmaf(k, b2f(e[jj]), o[c8*8 + jj]);
      }
    }
  }

  u16* wp = y2pad + ((size_t)(n*PD + h + 1)*PD + (t + 1))*CIN;
  #pragma unroll
  for (int c8 = 0; c8 < 8; ++c8){
    u16 ob[8];
    #pragma unroll
    for (int jj = 0; jj < 8; ++jj) ob[jj] = f2b(o[c8*8 + jj]);
    *(uint4*)(wp + c8*8) = *(uint4*)ob;
  }

  #pragma unroll
  for (int c = 0; c < 32; ++c) ov[t][c] = o[c];
  __syncthreads();
  {
    int c = t & 31, seg = t >> 5;
    float s = 0.f, q = 0.f;
    #pragma unroll
    for (int rr = 0; rr < 32; ++rr){
      float v = ov[seg*32 + rr][c];
      s += v; q += v*v;
    }
    ps[seg][c][0] = s; ps[seg][c][1] = q;
  }
  __syncthreads();
  if (t < 64){
    int c = t >> 1, which = t & 1;
    float v = 0.f;
    #pragma unroll
    for (int seg = 0; seg < 8; ++seg) v += ps[seg][c][which];
    atomicAdd(which ? &hinsumsq[n*32 + c] : &hinsum[n*32 + c], v);
  }
}

__global__ void hinfinal_kernel(const float* __restrict__ hinsum, const float* __restrict__ hinsumsq,
                                float* __restrict__ hmu, float* __restrict__ hrs){
  int i = threadIdx.x;
  if (i < 128){
    const float M = 65536.f;
    float mu  = hinsum[i] / M;
    float var = hinsumsq[i] / M - mu*mu;
    hmu[i] = mu;
    hrs[i] = rsqrtf(var + EPSV);
  }
}

// ---------- HIN apply + leaky in place on y2pad; zero the pad ring ----------
__global__ __launch_bounds__(256) void hinapply_kernel(u16* __restrict__ y2pad,
                                                       const float* __restrict__ hmu,
                                                       const float* __restrict__ hrs){
  int n = blockIdx.x / PD, pr = blockIdx.x % PD, t = threadIdx.x;
  u16* row = y2pad + (size_t)(n*PD + pr)*PD*CIN;
  bool ringrow = (pr == 0) || (pr == PD-1);
  for (int idx = t; idx < PD*8; idx += 256){
    int px = idx >> 3, cc = idx & 7;
    uint4* p = (uint4*)(row + (size_t)px*CIN + cc*8);
    if (ringrow || px == 0 || px == PD-1){
      uint4 z = {0,0,0,0}; *p = z; continue;
    }
    uint4 v = *p;
    u16* e = (u16*)&v;
    if (cc < 4){
      int cb = n*32 + cc*8;
      #pragma unroll
      for (int j = 0; j < 8; ++j){
        float f = (b2f(e[j]) - hmu[cb+j]) * hrs[cb+j];
        e[j] = f2b(leakyf(f));
      }
    } else {
      #pragma unroll
      for (int j = 0; j < 8; ++j) e[j] = f2b(leakyf(b2f(e[j])));
    }
    *p = v;
  }
}

// ---------- launch ----------
extern "C" void kernel_launch(void* const* d_in, const int* in_sizes, int n_in,
                              void* d_out, int out_size, void* d_ws, size_t ws_size,
                              hipStream_t stream){
  const float* x     = (const float*)d_in[0];
  const float* w1    = (const float*)d_in[1];
  const float* b1    = (const float*)d_in[2];
  const float* wf    = (const float*)d_in[3];
  const float* gamma = (const float*)d_in[4];
  const float* beta  = (const float*)d_in[5];
  const float* w2    = (const float*)d_in[6];
  const float* b2    = (const float*)d_in[7];
  const float* wr    = (const float*)d_in[8];
  const float* br    = (const float*)d_in[9];

  char* ws = (char*)d_ws;
  const size_t PADB = (size_t)NN*PD*PD*CIN*2;   // 34,080,768 bytes
  u16* xpad  = (u16*)(ws);
  u16* y1pad = (u16*)(ws + PADB);
  u16* y2pad = (u16*)(ws + 2*PADB);
  float* stats = (float*)(ws + 3*PADB);
  float* bnsum   = stats;        float* bnsumsq = stats + 80;
  float* bnscale = stats + 160;  float* bnshift = stats + 240;
  float* hinsum  = stats + 320;  float* hinsumsq= stats + 448;
  float* hmu     = stats + 576;  float* hrs     = stats + 704;
  u16* wB1 = (u16*)(ws + 3*PADB + 4096);
  u16* wBf = wB1 + 36864;
  u16* wB2 = wBf + 46080;
  u16* wBr = wB2 + 36864;

  u16* sig = (u16*)d_out;        // 41.9MB bf16, overwritten by conv2's f32 output later
  float* out = (float*)d_out;

  hipMemsetAsync(stats, 0, 4096, stream);
  prep_kernel<<<180, 256, 0, stream>>>(w1, wf, w2, wr, wB1, wBf, wB2, wBr);
  padx_kernel<<<NN*HH, 256, 0, stream>>>(x, xpad);
  conv_mfma<4,0><<<2048, 256, 0, stream>>>(xpad, wB1, b1, y1pad, nullptr, nullptr, nullptr, nullptr, nullptr, nullptr);
  reflect_kernel<<<(4*1028*8 + 255)/256, 256, 0, stream>>>(y1pad);
  conv_mfma<5,1><<<2048, 256, 0, stream>>>(y1pad, wBf, nullptr, sig, nullptr, nullptr, nullptr, nullptr, bnsum, bnsumsq);
  bnfinal_kernel<<<1, 80, 0, stream>>>(bnsum, bnsumsq, gamma, beta, bnscale, bnshift);
  filter_kernel<<<NN*HH, 256, 0, stream>>>(sig, y1pad, bnscale, bnshift, y2pad, hinsum, hinsumsq);
  hinfinal_kernel<<<1, 128, 0, stream>>>(hinsum, hinsumsq, hmu, hrs);
  hinapply_kernel<<<NN*PD, 256, 0, stream>>>(y2pad, hmu, hrs);
  conv_mfma<4,2><<<2048, 256, 0, stream>>>(y2pad, wB2, b2, nullptr, out, xpad, wBr, br, nullptr, nullptr);
}